// Round 9
// baseline (1433.262 us; speedup 1.0000x reference)
//
#include <hip/hip_runtime.h>

// RGCN on MI355X — round 9: fused transform+aggregate (no t materialization).
// Evidence r5-r8: every GEMM/store variant pinned at ~2 TB/s; pipeline moved
// ~660 MB -> ~330 µs floor. Fix: cut bytes. Per (dst-tile32, rel) edge buckets
// (padded to 16); kernel holds hacc[32][NOUT] fp32 in LDS, stages W[r] in LDS,
// waves process 16-edge chunks: A-frags direct from cache-resident bf16 A,
// MFMA, scatter msg*norm into hacc via LDS float atomics. One coalesced
// output write. Both 200MB t buffers + both gather kernels eliminated.

#define R_NUM 16

typedef __attribute__((ext_vector_type(8))) short bf16x8;
typedef __attribute__((ext_vector_type(4))) float f32x4;

__device__ __forceinline__ float bf2f(unsigned short u) {
    unsigned int x = ((unsigned int)u) << 16;
    return __builtin_bit_cast(float, x);
}
__device__ __forceinline__ unsigned short f2bf(float f) {
    unsigned int x = __builtin_bit_cast(unsigned int, f);
    x += 0x7FFFu + ((x >> 16) & 1u);  // RNE
    return (unsigned short)(x >> 16);
}
__device__ __forceinline__ unsigned pack2(float a, float b) {
    return (unsigned)f2bf(a) | ((unsigned)f2bf(b) << 16);
}
__device__ __forceinline__ float lo16(unsigned v) { return bf2f((unsigned short)(v & 0xFFFF)); }
__device__ __forceinline__ float hi16(unsigned v) { return bf2f((unsigned short)(v >> 16)); }

// ---------------- dtype sniffer (fp32 vs bf16 harness inputs) ----------------
__global__ void detect_dtype(const unsigned short* __restrict__ raw, int* flag) {
    __shared__ int tot;
    if (threadIdx.x == 0) tot = 0;
    __syncthreads();
    int c = 0;
    for (int i = threadIdx.x; i < 4096; i += 256) {
        unsigned short u = raw[2 * i];
        int e = (u >> 7) & 0xFF;
        if (e >= 113 && e <= 134) c++;
    }
    atomicAdd(&tot, c);
    __syncthreads();
    if (threadIdx.x == 0) *flag = (tot > 2048) ? 1 : 0;  // 1 => bf16 inputs
}

// feat -> bf16 canonical buffer
__global__ void cast_feat(const void* __restrict__ in, unsigned short* __restrict__ out,
                          int n, const int* __restrict__ flagp) {
    int flag = *flagp;
    int g = blockIdx.x * 256 + threadIdx.x;
    if (g * 8 >= n) return;
    if (flag) {
        ((uint4*)out)[g] = ((const uint4*)in)[g];
    } else {
        const float* f = (const float*)in + g * 8;
        uint4 v;
        v.x = pack2(f[0], f[1]);
        v.y = pack2(f[2], f[3]);
        v.z = pack2(f[4], f[5]);
        v.w = pack2(f[6], f[7]);
        ((uint4*)out)[g] = v;
    }
}

// Both weight transposes in one launch: W[r][k][o] -> Wt[r][o][k] bf16.
__global__ void transpose_both(const void* __restrict__ W1, const void* __restrict__ W2,
                               unsigned short* __restrict__ w1t, unsigned short* __restrict__ w2t,
                               const int* __restrict__ flagp) {
    const int flag = *flagp;
    const int n1 = R_NUM * 128 * 128;
    const int n2 = R_NUM * 128 * 64;
    int idx = blockIdx.x * 256 + threadIdx.x;
    if (idx < n1) {
        int k = idx % 128, o = (idx / 128) % 128, r = idx / (128 * 128);
        int iin = (r * 128 + k) * 128 + o;
        float v = flag ? bf2f(((const unsigned short*)W1)[iin]) : ((const float*)W1)[iin];
        w1t[idx] = f2bf(v);
    } else if (idx < n1 + n2) {
        int j = idx - n1;
        int k = j % 128, o = (j / 128) % 64, r = j / (128 * 64);
        int iin = (r * 128 + k) * 64 + o;
        float v = flag ? bf2f(((const unsigned short*)W2)[iin]) : ((const float*)W2)[iin];
        w2t[j] = f2bf(v);
    }
}

// ---------------- bucket CSR: key = (dst>>5)*16 + et, counts padded to 16 ----
__global__ void hist_bucket(const int* __restrict__ dst, const int* __restrict__ et,
                            int* __restrict__ counts, int nedges) {
    int e = blockIdx.x * 256 + threadIdx.x;
    if (e < nedges) atomicAdd(&counts[(dst[e] >> 5) * 16 + (et[e] & 15)], 1);
}

__global__ __launch_bounds__(256) void scan_phase1(const int* __restrict__ counts,
                                                   int* __restrict__ blocksums, int n) {
    __shared__ int red[256];
    int base = blockIdx.x * 1024 + threadIdx.x * 4;
    int s = 0;
#pragma unroll
    for (int j = 0; j < 4; j++) {
        int idx = base + j;
        if (idx < n) s += (counts[idx] + 15) & ~15;  // padded
    }
    red[threadIdx.x] = s;
    __syncthreads();
    for (int d = 128; d > 0; d >>= 1) {
        if (threadIdx.x < d) red[threadIdx.x] += red[threadIdx.x + d];
        __syncthreads();
    }
    if (threadIdx.x == 0) blocksums[blockIdx.x] = red[0];
}

__global__ __launch_bounds__(1024) void scan_phase2(const int* __restrict__ blocksums,
                                                    int* __restrict__ blockoff, int nb) {
    __shared__ int arr[1024];
    int t = threadIdx.x;
    arr[t] = (t < nb) ? blocksums[t] : 0;
    __syncthreads();
    for (int d = 1; d < 1024; d <<= 1) {
        int v = (t >= d) ? arr[t - d] : 0;
        __syncthreads();
        arr[t] += v;
        __syncthreads();
    }
    if (t < nb) blockoff[t] = (t == 0) ? 0 : arr[t - 1];
}

__global__ __launch_bounds__(256) void scan_phase3(const int* __restrict__ counts,
                                                   const int* __restrict__ blockoff,
                                                   int* __restrict__ offsets,
                                                   int* __restrict__ cursor, int n) {
    __shared__ int tsum[256];
    int base = blockIdx.x * 1024 + threadIdx.x * 4;
    int c[4];
    int s = 0;
#pragma unroll
    for (int j = 0; j < 4; j++) {
        int idx = base + j;
        c[j] = (idx < n) ? ((counts[idx] + 15) & ~15) : 0;  // padded
        s += c[j];
    }
    tsum[threadIdx.x] = s;
    __syncthreads();
    for (int d = 1; d < 256; d <<= 1) {
        int v = (threadIdx.x >= d) ? tsum[threadIdx.x - d] : 0;
        __syncthreads();
        tsum[threadIdx.x] += v;
        __syncthreads();
    }
    int run = blockoff[blockIdx.x] + ((threadIdx.x == 0) ? 0 : tsum[threadIdx.x - 1]);
#pragma unroll
    for (int j = 0; j < 4; j++) {
        int idx = base + j;
        if (idx < n) {
            offsets[idx] = run;
            cursor[idx] = run;
            if (idx == n - 1) offsets[n] = run + c[j];
            run += c[j];
        }
    }
}

// payload: x = src<<6 | (dst&31); y = norm fp32. Pad slots stay 0 (norm=0).
__global__ void fill_payload(const int* __restrict__ src, const int* __restrict__ dst,
                             const int* __restrict__ et, const void* __restrict__ nrm,
                             const int* __restrict__ flagp, int* __restrict__ cursor,
                             uint2* __restrict__ payload, int nedges) {
    int e = blockIdx.x * 256 + threadIdx.x;
    if (e >= nedges) return;
    int flag = *flagp;
    float nm = flag ? bf2f(((const unsigned short*)nrm)[e]) : ((const float*)nrm)[e];
    int d = dst[e];
    int key = (d >> 5) * 16 + (et[e] & 15);
    int pos = atomicAdd(&cursor[key], 1);
    uint2 pl;
    pl.x = ((unsigned)src[e] << 6) | (unsigned)(d & 31);
    pl.y = __builtin_bit_cast(unsigned, nm);
    payload[pos] = pl;
}

// ---------------- fused transform + aggregate ----------------
// Block = dst-tile of 32 nodes. hacc[32][NOUT] fp32 in LDS (+1 pad col).
// Per rel: stage W[r] (NOUT x 128, LDS). Waves independently take 16-edge
// chunks: A-frag(lane) = Ab[src(mr)] k-segment (direct global, cache-hot);
// D=mfma(A,B): row=edge(quad*4+reg), col=nt*16+mr -> atomicAdd into
// hacc[dl][col] * norm. Epilogue: coalesced store (relu+bf16 or flag dtype).
template <int NOUT, int OUTMODE>
__global__ __launch_bounds__(256) void edge_agg(const unsigned short* __restrict__ Ab,
                                                const unsigned short* __restrict__ Wt,
                                                const int* __restrict__ offs,
                                                const uint2* __restrict__ payload,
                                                void* __restrict__ out, int nnodes,
                                                const int* __restrict__ flagp) {
    constexpr int LDB = 136;
    constexpr int LDH = NOUT + 1;
    constexpr int NT = NOUT / 16;
    __shared__ unsigned short lB[NOUT * LDB];
    __shared__ float hacc[32 * LDH];
    const int tid = threadIdx.x;
    const int tile = blockIdx.x;
    const int node0 = tile * 32;

    for (int i = tid; i < 32 * LDH; i += 256) hacc[i] = 0.f;

    const int w = tid >> 6, lane = tid & 63;
    const int quad = lane >> 4, mr = lane & 15;

    for (int r = 0; r < R_NUM; r++) {
        const int beg = offs[tile * 16 + r];
        const int end = offs[tile * 16 + r + 1];
        if (beg == end) continue;          // block-uniform
        __syncthreads();                   // prior rel's lB readers done
        for (int i = tid; i < NOUT * 16; i += 256) {
            int o = i >> 4, seg = i & 15;
            *(uint4*)(lB + o * LDB + seg * 8) =
                *(const uint4*)(Wt + ((size_t)r * NOUT + o) * 128 + seg * 8);
        }
        __syncthreads();

        const int nch = (end - beg) >> 4;  // padded => exact
        for (int c = w; c < nch; c += 4) {
            const int base = beg + c * 16;
            uint2 pl = make_uint2(0u, 0u);
            if (lane < 16) pl = payload[base + lane];
            // A fragments: edge row m = mr
            unsigned keym = (unsigned)__shfl((int)pl.x, mr);
            const unsigned short* arow = Ab + (size_t)(keym >> 6) * 128;
            bf16x8 af[4];
#pragma unroll
            for (int kk = 0; kk < 4; kk++)
                af[kk] = *(const bf16x8*)(arow + kk * 32 + quad * 8);
            // dst-local + norm for edges m = quad*4 + g
            int dl[4];
            float nm[4];
#pragma unroll
            for (int g = 0; g < 4; g++) {
                int e = quad * 4 + g;
                dl[g] = (int)(((unsigned)__shfl((int)pl.x, e)) & 63u);
                nm[g] = __builtin_bit_cast(float, (unsigned)__shfl((int)pl.y, e));
            }
#pragma unroll
            for (int nt = 0; nt < NT; nt++) {
                f32x4 acc;
                acc = 0.f;
#pragma unroll
                for (int kk = 0; kk < 4; kk++) {
                    bf16x8 b = *(const bf16x8*)(lB + (nt * 16 + mr) * LDB + kk * 32 + quad * 8);
                    acc = __builtin_amdgcn_mfma_f32_16x16x32_bf16(af[kk], b, acc, 0, 0, 0);
                }
                const int col = nt * 16 + mr;
#pragma unroll
                for (int g = 0; g < 4; g++)
                    atomicAdd(&hacc[dl[g] * LDH + col], acc[g] * nm[g]);
            }
        }
    }
    __syncthreads();

    // epilogue: coalesced write
    if (OUTMODE == 0) {
        // h = relu(hacc) bf16, NOUT=128: 8 thr/node, 16 cols each
        int nl = tid >> 3, colb = (tid & 7) * 16;
        int node = node0 + nl;
        if (node < nnodes) {
            const float* hp = hacc + nl * LDH + colb;
            uint4 v0, v1;
            v0.x = pack2(fmaxf(hp[0], 0.f), fmaxf(hp[1], 0.f));
            v0.y = pack2(fmaxf(hp[2], 0.f), fmaxf(hp[3], 0.f));
            v0.z = pack2(fmaxf(hp[4], 0.f), fmaxf(hp[5], 0.f));
            v0.w = pack2(fmaxf(hp[6], 0.f), fmaxf(hp[7], 0.f));
            v1.x = pack2(fmaxf(hp[8], 0.f), fmaxf(hp[9], 0.f));
            v1.y = pack2(fmaxf(hp[10], 0.f), fmaxf(hp[11], 0.f));
            v1.z = pack2(fmaxf(hp[12], 0.f), fmaxf(hp[13], 0.f));
            v1.w = pack2(fmaxf(hp[14], 0.f), fmaxf(hp[15], 0.f));
            uint4* dst4 = (uint4*)((unsigned short*)out + (size_t)node * NOUT + colb);
            dst4[0] = v0;
            dst4[1] = v1;
        }
    } else {
        // final out, NOUT=64: 8 thr/node, 8 cols each
        int nl = tid >> 3, colb = (tid & 7) * 8;
        int node = node0 + nl;
        if (node < nnodes) {
            const float* hp = hacc + nl * LDH + colb;
            if (*flagp) {
                uint4 v;
                v.x = pack2(hp[0], hp[1]);
                v.y = pack2(hp[2], hp[3]);
                v.z = pack2(hp[4], hp[5]);
                v.w = pack2(hp[6], hp[7]);
                *(uint4*)((unsigned short*)out + (size_t)node * NOUT + colb) = v;
            } else {
                float4 a = make_float4(hp[0], hp[1], hp[2], hp[3]);
                float4 b = make_float4(hp[4], hp[5], hp[6], hp[7]);
                float4* dst4 = (float4*)((float*)out + (size_t)node * NOUT + colb);
                dst4[0] = a;
                dst4[1] = b;
            }
        }
    }
}

// ---------------- fallback path (chunked + atomics, node-major t) ----------------
template <int NOUT, int AMODE>
__global__ __launch_bounds__(256) void gemm_rel(const void* __restrict__ Asrc,
                                                const unsigned short* __restrict__ Wt,
                                                unsigned short* __restrict__ T, int nnodes,
                                                int rbase, const int* __restrict__ flagp) {
    constexpr int LDA = 136;
    __shared__ unsigned short lA[64 * LDA];
    __shared__ unsigned short lB[NOUT * LDA];
    const int tid = threadIdx.x;
    const int node0 = blockIdx.x * 64;
    const int rel = rbase + blockIdx.y;
    const int Gr = gridDim.y;
    const int flag = (AMODE == 0) ? *flagp : 1;

    for (int i = tid; i < 64 * 16; i += 256) {
        int row = i >> 4, seg = i & 15;
        int node = node0 + row;
        uint4 v = make_uint4(0u, 0u, 0u, 0u);
        if (node < nnodes) {
            if (AMODE == 1) {
                const float* p = (const float*)Asrc + (size_t)node * 128 + seg * 8;
                float4 f0 = ((const float4*)p)[0];
                float4 f1 = ((const float4*)p)[1];
                v.x = pack2(fmaxf(f0.x, 0.f), fmaxf(f0.y, 0.f));
                v.y = pack2(fmaxf(f0.z, 0.f), fmaxf(f0.w, 0.f));
                v.z = pack2(fmaxf(f1.x, 0.f), fmaxf(f1.y, 0.f));
                v.w = pack2(fmaxf(f1.z, 0.f), fmaxf(f1.w, 0.f));
            } else if (flag) {
                v = *(const uint4*)((const unsigned short*)Asrc + (size_t)node * 128 + seg * 8);
            } else {
                const float* p = (const float*)Asrc + (size_t)node * 128 + seg * 8;
                float4 f0 = ((const float4*)p)[0];
                float4 f1 = ((const float4*)p)[1];
                v.x = pack2(f0.x, f0.y);
                v.y = pack2(f0.z, f0.w);
                v.z = pack2(f1.x, f1.y);
                v.w = pack2(f1.z, f1.w);
            }
        }
        *(uint4*)(lA + row * LDA + seg * 8) = v;
    }
    for (int i = tid; i < NOUT * 16; i += 256) {
        int o = i >> 4, seg = i & 15;
        *(uint4*)(lB + o * LDA + seg * 8) =
            *(const uint4*)(Wt + ((size_t)rel * NOUT + o) * 128 + seg * 8);
    }
    __syncthreads();

    const int w = tid >> 6, lane = tid & 63;
    const int quad = lane >> 4, mr = lane & 15;
    constexpr int NT = NOUT / 16;
    f32x4 acc[NT];
#pragma unroll
    for (int t = 0; t < NT; t++) acc[t] = 0.f;
    const unsigned short* pa = lA + (w * 16 + mr) * LDA + quad * 8;
    const unsigned short* pb = lB + mr * LDA + quad * 8;
#pragma unroll
    for (int kk = 0; kk < 4; kk++) {
        bf16x8 a = *(const bf16x8*)(pa + kk * 32);
#pragma unroll
        for (int nt = 0; nt < NT; nt++) {
            bf16x8 b = *(const bf16x8*)(pb + nt * 16 * LDA + kk * 32);
            acc[nt] = __builtin_amdgcn_mfma_f32_16x16x32_bf16(a, b, acc[nt], 0, 0, 0);
        }
    }
#pragma unroll
    for (int nt = 0; nt < NT; nt++)
#pragma unroll
        for (int reg = 0; reg < 4; reg++) {
            int node = node0 + w * 16 + quad * 4 + reg;
            if (node < nnodes)
                T[((size_t)node * Gr + blockIdx.y) * NOUT + nt * 16 + mr] = f2bf(acc[nt][reg]);
        }
}

template <int NOUT>
__global__ void scatter_k(const unsigned short* __restrict__ T, int Gr, int rbase,
                          const void* __restrict__ nrm, const int* __restrict__ flagp,
                          const int* __restrict__ src, const int* __restrict__ dst,
                          const int* __restrict__ et, float* __restrict__ accum, int nedges) {
    constexpr int LPE = NOUT / 2;
    const int flag = *flagp;
    const int epb = 256 / LPE;
    const int sub = threadIdx.x % LPE;
    const int slot = threadIdx.x / LPE;
    for (int e = blockIdx.x * epb + slot; e < nedges; e += gridDim.x * epb) {
        int g = et[e] - rbase;
        if (g < 0 || g >= Gr) continue;
        int s = src[e], d = dst[e];
        float nm = flag ? bf2f(((const unsigned short*)nrm)[e]) : ((const float*)nrm)[e];
        unsigned pv = ((const unsigned*)(T + ((size_t)s * Gr + g) * NOUT))[sub];
        float* p = accum + (size_t)d * NOUT + sub * 2;
        unsafeAtomicAdd(p, lo16(pv) * nm);
        unsafeAtomicAdd(p + 1, hi16(pv) * nm);
    }
}

__global__ void write_out(const float* __restrict__ acc, void* __restrict__ dout, int n,
                          const int* __restrict__ flagp) {
    int flag = *flagp;
    int i = blockIdx.x * 256 + threadIdx.x;
    if (i >= n) return;
    float v = acc[i];
    if (flag) ((unsigned short*)dout)[i] = f2bf(v);
    else      ((float*)dout)[i] = v;
}

extern "C" void kernel_launch(void* const* d_in, const int* in_sizes, int n_in,
                              void* d_out, int out_size, void* d_ws, size_t ws_size,
                              hipStream_t stream) {
    const void* feat = d_in[0];
    const void* norm = d_in[1];
    const void* W1 = d_in[2];
    const void* W2 = d_in[3];
    const int* src = (const int*)d_in[4];
    const int* dst = (const int*)d_in[5];
    const int* et  = (const int*)d_in[6];

    const int nnodes = in_sizes[0] / 128;
    const int nedges = in_sizes[1];

    char* ws = (char*)d_ws;
    size_t off = 0;
    auto alloc = [&](size_t bytes) { size_t o = off; off += (bytes + 255) & ~255ULL; return o; };
    size_t off_flag = alloc(4);
    size_t off_w1t  = alloc((size_t)R_NUM * 128 * 128 * 2);
    size_t off_w2t  = alloc((size_t)R_NUM * 64 * 128 * 2);

    int* flagp = (int*)(ws + off_flag);
    unsigned short* w1t = (unsigned short*)(ws + off_w1t);
    unsigned short* w2t = (unsigned short*)(ws + off_w2t);

    // fast-path layout
    const int ntiles = (nnodes + 31) / 32;
    const int nbuckets = ntiles * 16;
    const int paycap = nedges + nbuckets * 15;
    size_t f_off = off;
    auto falloc = [&](size_t bytes) { size_t o = f_off; f_off += (bytes + 255) & ~255ULL; return o; };
    size_t off_featb = falloc((size_t)nnodes * 128 * 2);
    size_t off_h     = falloc((size_t)nnodes * 128 * 2);
    size_t off_offs  = falloc((size_t)(nbuckets + 1) * 4);
    size_t off_curs  = falloc((size_t)nbuckets * 4);
    size_t off_cnt   = falloc((size_t)nbuckets * 4);
    size_t off_bsum  = falloc(1024 * 4);
    size_t off_boff  = falloc(1024 * 4);
    size_t off_pay   = falloc((size_t)paycap * 8);
    const int nb = (nbuckets + 1023) / 1024;
    bool fast = (f_off <= ws_size) && (nb <= 1024);

    const int ntr = R_NUM * 128 * 128 + R_NUM * 128 * 64;

    detect_dtype<<<1, 256, 0, stream>>>((const unsigned short*)feat, flagp);
    transpose_both<<<(ntr + 255) / 256, 256, 0, stream>>>(W1, W2, w1t, w2t, flagp);

    if (fast) {
        unsigned short* featb = (unsigned short*)(ws + off_featb);
        unsigned short* h = (unsigned short*)(ws + off_h);
        int* offs = (int*)(ws + off_offs);
        int* curs = (int*)(ws + off_curs);
        int* cnt  = (int*)(ws + off_cnt);
        int* bsum = (int*)(ws + off_bsum);
        int* boff = (int*)(ws + off_boff);
        uint2* pay = (uint2*)(ws + off_pay);

        int nfeat = nnodes * 128;
        cast_feat<<<(nfeat / 8 + 255) / 256, 256, 0, stream>>>(feat, featb, nfeat, flagp);

        hipMemsetAsync(cnt, 0, (size_t)nbuckets * 4, stream);
        hipMemsetAsync(pay, 0, (size_t)paycap * 8, stream);
        hist_bucket<<<(nedges + 255) / 256, 256, 0, stream>>>(dst, et, cnt, nedges);
        scan_phase1<<<nb, 256, 0, stream>>>(cnt, bsum, nbuckets);
        scan_phase2<<<1, 1024, 0, stream>>>(bsum, boff, nb);
        scan_phase3<<<nb, 256, 0, stream>>>(cnt, boff, offs, curs, nbuckets);
        fill_payload<<<(nedges + 255) / 256, 256, 0, stream>>>(src, dst, et, norm, flagp,
                                                               curs, pay, nedges);

        edge_agg<128, 0><<<ntiles, 256, 0, stream>>>(featb, w1t, offs, pay, h, nnodes, flagp);
        edge_agg<64, 1><<<ntiles, 256, 0, stream>>>(h, w2t, offs, pay, d_out, nnodes, flagp);
        return;
    }

    // fallback: chunked atomic path
    size_t off_hpre = alloc((size_t)nnodes * 128 * 4);
    size_t off_oacc = alloc((size_t)nnodes * 64 * 4);
    size_t t_cap = (ws_size > off) ? (ws_size - off) : 0;
    auto pick_gr = [&](int ncol) {
        int gr = 0;
        for (int g = 16; g >= 1; g >>= 1)
            if ((size_t)nnodes * g * ncol * 2 <= t_cap) { gr = g; break; }
        return gr;
    };
    int Gr1 = pick_gr(128);
    int Gr2 = pick_gr(64);
    if (Gr1 < 1 || Gr2 < 1) {
        hipMemsetAsync(d_out, 0x42, (size_t)out_size * 2, stream);
        return;
    }
    float* hpre = (float*)(ws + off_hpre);
    float* oacc = (float*)(ws + off_oacc);
    unsigned short* t = (unsigned short*)(ws + off);
    const int gx = (nnodes + 63) / 64;

    hipMemsetAsync(hpre, 0, (size_t)nnodes * 128 * 4, stream);
    hipMemsetAsync(oacc, 0, (size_t)nnodes * 64 * 4, stream);
    for (int rb = 0; rb < R_NUM; rb += Gr1) {
        gemm_rel<128, 0><<<dim3(gx, Gr1), 256, 0, stream>>>(feat, w1t, t, nnodes, rb, flagp);
        scatter_k<128><<<4096, 256, 0, stream>>>(t, Gr1, rb, norm, flagp, src, dst, et, hpre, nedges);
    }
    for (int rb = 0; rb < R_NUM; rb += Gr2) {
        gemm_rel<64, 1><<<dim3(gx, Gr2), 256, 0, stream>>>(hpre, w2t, t, nnodes, rb, flagp);
        scatter_k<64><<<4096, 256, 0, stream>>>(t, Gr2, rb, norm, flagp, src, dst, et, oacc, nedges);
    }
    int nout = nnodes * 64;
    write_out<<<(nout + 255) / 256, 256, 0, stream>>>(oacc, d_out, nout, flagp);
}

// Round 10
// 407.258 us; speedup vs baseline: 3.5193x; 3.5193x over previous
//
#include <hip/hip_runtime.h>

// RGCN on MI355X — round 10: revert to r7 pipeline (best: 398 µs), replace
// GEMM with a BARRIER-FREE rel-loop: A staged to LDS once (one barrier),
// A-frags hoisted to regs, B-fragments loaded per-MFMA directly from global
// (Wt = 0.5 MB, L2-hot), acc stored directly (transposed-MFMA layout, r7/r8
// verified). No __syncthreads in the loop -> no vmcnt(0) drains -> stores
// overlap next rel's compute. r9's fused kernel (842 µs, latency-serialized)
// abandoned.

#define R_NUM 16

typedef __attribute__((ext_vector_type(8))) short bf16x8;
typedef __attribute__((ext_vector_type(4))) float f32x4;

__device__ __forceinline__ float bf2f(unsigned short u) {
    unsigned int x = ((unsigned int)u) << 16;
    return __builtin_bit_cast(float, x);
}
__device__ __forceinline__ unsigned short f2bf(float f) {
    unsigned int x = __builtin_bit_cast(unsigned int, f);
    x += 0x7FFFu + ((x >> 16) & 1u);  // RNE
    return (unsigned short)(x >> 16);
}
__device__ __forceinline__ unsigned pack2(float a, float b) {
    return (unsigned)f2bf(a) | ((unsigned)f2bf(b) << 16);
}
__device__ __forceinline__ float lo16(unsigned v) { return bf2f((unsigned short)(v & 0xFFFF)); }
__device__ __forceinline__ float hi16(unsigned v) { return bf2f((unsigned short)(v >> 16)); }

// ---------------- dtype sniffer (fp32 vs bf16 harness inputs) ----------------
__global__ void detect_dtype(const unsigned short* __restrict__ raw, int* flag) {
    __shared__ int tot;
    if (threadIdx.x == 0) tot = 0;
    __syncthreads();
    int c = 0;
    for (int i = threadIdx.x; i < 4096; i += 256) {
        unsigned short u = raw[2 * i];
        int e = (u >> 7) & 0xFF;
        if (e >= 113 && e <= 134) c++;
    }
    atomicAdd(&tot, c);
    __syncthreads();
    if (threadIdx.x == 0) *flag = (tot > 2048) ? 1 : 0;  // 1 => bf16 inputs
}

// Both weight transposes in one launch: W[r][k][o] -> Wt[r][o][k] bf16.
__global__ void transpose_both(const void* __restrict__ W1, const void* __restrict__ W2,
                               unsigned short* __restrict__ w1t, unsigned short* __restrict__ w2t,
                               const int* __restrict__ flagp) {
    const int flag = *flagp;
    const int n1 = R_NUM * 128 * 128;
    const int n2 = R_NUM * 128 * 64;
    int idx = blockIdx.x * 256 + threadIdx.x;
    if (idx < n1) {
        int k = idx % 128, o = (idx / 128) % 128, r = idx / (128 * 128);
        int iin = (r * 128 + k) * 128 + o;
        float v = flag ? bf2f(((const unsigned short*)W1)[iin]) : ((const float*)W1)[iin];
        w1t[idx] = f2bf(v);
    } else if (idx < n1 + n2) {
        int j = idx - n1;
        int k = j % 128, o = (j / 128) % 64, r = j / (128 * 64);
        int iin = (r * 128 + k) * 64 + o;
        float v = flag ? bf2f(((const unsigned short*)W2)[iin]) : ((const float*)W2)[iin];
        w2t[j] = f2bf(v);
    }
}

// ---------------- barrier-free GEMM over all relations ----------------
// Block = 64-node tile. LDS = A-tile only. One barrier (after A staging).
// Per rel: 8 (NOUT=128) global B-frag loads from L2-hot Wt, 32 MFMA
// (transposed: acc=mfma(B,A) -> lane owns node=mt*16+mr, cols quad*4+..),
// 8 direct uint2 stores to rel-major T[rel][node][NOUT]. No barriers ->
// stores drain during subsequent compute.
template <int NOUT, int AMODE>
__global__ __launch_bounds__(256, 3) void gemm_nb(const void* __restrict__ Asrc,
                                                  const unsigned short* __restrict__ Wt,
                                                  unsigned short* __restrict__ T, int nnodes,
                                                  const int* __restrict__ flagp) {
    constexpr int LDA = 136;
    constexpr int NTC = NOUT / 64;
    __shared__ unsigned short lA[64 * LDA];
    const int tid = threadIdx.x;
    const int node0 = blockIdx.x * 64;
    const int flag = (AMODE == 0) ? *flagp : 1;

    // stage A: 64 rows x 16 segs x 8 bf16
    for (int i = tid; i < 64 * 16; i += 256) {
        int row = i >> 4, seg = i & 15;
        int node = node0 + row;
        uint4 v = make_uint4(0u, 0u, 0u, 0u);
        if (node < nnodes) {
            if (AMODE == 2 || flag) {
                v = *(const uint4*)((const unsigned short*)Asrc + (size_t)node * 128 + seg * 8);
            } else {
                const float* p = (const float*)Asrc + (size_t)node * 128 + seg * 8;
                float4 f0 = ((const float4*)p)[0];
                float4 f1 = ((const float4*)p)[1];
                v.x = pack2(f0.x, f0.y);
                v.y = pack2(f0.z, f0.w);
                v.z = pack2(f1.x, f1.y);
                v.w = pack2(f1.z, f1.w);
            }
        }
        *(uint4*)(lA + row * LDA + seg * 8) = v;
    }
    __syncthreads();  // the only barrier

    const int w = tid >> 6, lane = tid & 63;
    const int quad = lane >> 4, mr = lane & 15;

    // hoist all 16 A-fragments into registers
    bf16x8 afr[16];
#pragma unroll
    for (int mt = 0; mt < 4; mt++)
#pragma unroll
        for (int kk = 0; kk < 4; kk++)
            afr[mt * 4 + kk] = *(const bf16x8*)(lA + (mt * 16 + mr) * LDA + kk * 32 + quad * 8);

    // per-wave B row base: row = c*64 + w*16 + mr, col segment = kk*32 + quad*8
    const unsigned short* wb = Wt + (size_t)(w * 16 + mr) * 128 + quad * 8;

    for (int rel = 0; rel < R_NUM; rel++) {
        const unsigned short* wr = wb + (size_t)rel * NOUT * 128;
        bf16x8 bf[NTC][4];
#pragma unroll
        for (int c = 0; c < NTC; c++)
#pragma unroll
            for (int kk = 0; kk < 4; kk++)
                bf[c][kk] = *(const bf16x8*)(wr + (size_t)c * 64 * 128 + kk * 32);

        f32x4 acc[4][NTC];
#pragma unroll
        for (int mt = 0; mt < 4; mt++)
#pragma unroll
            for (int c = 0; c < NTC; c++) acc[mt][c] = 0.f;

#pragma unroll
        for (int kk = 0; kk < 4; kk++)
#pragma unroll
            for (int c = 0; c < NTC; c++)
#pragma unroll
                for (int mt = 0; mt < 4; mt++)
                    acc[mt][c] = __builtin_amdgcn_mfma_f32_16x16x32_bf16(bf[c][kk],
                                                                         afr[mt * 4 + kk],
                                                                         acc[mt][c], 0, 0, 0);

        // direct transposed store: node = mt*16+mr, cols c*64 + w*16 + quad*4 + {0..3}
#pragma unroll
        for (int mt = 0; mt < 4; mt++) {
            int node = node0 + mt * 16 + mr;
            if (node < nnodes) {
#pragma unroll
                for (int c = 0; c < NTC; c++) {
                    uint2 pv;
                    pv.x = pack2(acc[mt][c][0], acc[mt][c][1]);
                    pv.y = pack2(acc[mt][c][2], acc[mt][c][3]);
                    *(uint2*)(T + ((size_t)rel * nnodes + node) * NOUT + c * 64 + w * 16 +
                              quad * 4) = pv;
                }
            }
        }
    }
}

// ---------------- CSR build ----------------
__global__ void hist_dst(const int* __restrict__ dst, int* __restrict__ counts, int nedges) {
    int e = blockIdx.x * 256 + threadIdx.x;
    if (e < nedges) atomicAdd(&counts[dst[e]], 1);
}

__global__ __launch_bounds__(256) void scan_phase1(const int* __restrict__ counts,
                                                   int* __restrict__ blocksums, int n) {
    __shared__ int red[256];
    int base = blockIdx.x * 1024 + threadIdx.x * 4;
    int s = 0;
#pragma unroll
    for (int j = 0; j < 4; j++) {
        int idx = base + j;
        if (idx < n) s += counts[idx];
    }
    red[threadIdx.x] = s;
    __syncthreads();
    for (int d = 128; d > 0; d >>= 1) {
        if (threadIdx.x < d) red[threadIdx.x] += red[threadIdx.x + d];
        __syncthreads();
    }
    if (threadIdx.x == 0) blocksums[blockIdx.x] = red[0];
}

__global__ __launch_bounds__(1024) void scan_phase2(const int* __restrict__ blocksums,
                                                    int* __restrict__ blockoff, int nb) {
    __shared__ int arr[1024];
    int t = threadIdx.x;
    arr[t] = (t < nb) ? blocksums[t] : 0;
    __syncthreads();
    for (int d = 1; d < 1024; d <<= 1) {
        int v = (t >= d) ? arr[t - d] : 0;
        __syncthreads();
        arr[t] += v;
        __syncthreads();
    }
    if (t < nb) blockoff[t] = (t == 0) ? 0 : arr[t - 1];
}

__global__ __launch_bounds__(256) void scan_phase3(const int* __restrict__ counts,
                                                   const int* __restrict__ blockoff,
                                                   int* __restrict__ offsets,
                                                   int* __restrict__ cursor, int n) {
    __shared__ int tsum[256];
    int base = blockIdx.x * 1024 + threadIdx.x * 4;
    int c[4];
    int s = 0;
#pragma unroll
    for (int j = 0; j < 4; j++) {
        int idx = base + j;
        c[j] = (idx < n) ? counts[idx] : 0;
        s += c[j];
    }
    tsum[threadIdx.x] = s;
    __syncthreads();
    for (int d = 1; d < 256; d <<= 1) {
        int v = (threadIdx.x >= d) ? tsum[threadIdx.x - d] : 0;
        __syncthreads();
        tsum[threadIdx.x] += v;
        __syncthreads();
    }
    int run = blockoff[blockIdx.x] + ((threadIdx.x == 0) ? 0 : tsum[threadIdx.x - 1]);
#pragma unroll
    for (int j = 0; j < 4; j++) {
        int idx = base + j;
        if (idx < n) {
            offsets[idx] = run;
            cursor[idx] = run;
            if (idx == n - 1) offsets[n] = run + c[j];
            run += c[j];
        }
    }
}

__global__ void fill_payload(const int* __restrict__ src, const int* __restrict__ dst,
                             const int* __restrict__ et, const void* __restrict__ nrm,
                             const int* __restrict__ flagp, int* __restrict__ cursor,
                             uint2* __restrict__ payload, int nedges) {
    int e = blockIdx.x * 256 + threadIdx.x;
    if (e >= nedges) return;
    int flag = *flagp;
    float nm = flag ? bf2f(((const unsigned short*)nrm)[e]) : ((const float*)nrm)[e];
    int pos = atomicAdd(&cursor[dst[e]], 1);
    uint2 pl;
    pl.x = ((unsigned)src[e] << 4) | (unsigned)(et[e] & 15);
    pl.y = __builtin_bit_cast(unsigned, nm);
    payload[pos] = pl;
}

// ---------------- dst-centric gather (atomic-free) ----------------
// T is rel-major: row = T[(et*nnodes + src)*NOUT].
template <int NOUT, int OUTMODE>
__global__ __launch_bounds__(256) void gather_seg(const unsigned short* __restrict__ T,
                                                  const int* __restrict__ offsets,
                                                  const uint2* __restrict__ payload,
                                                  void* __restrict__ out, int nnodes,
                                                  const int* __restrict__ flagp) {
    constexpr int SUBW = NOUT / 2;
    const int lane = threadIdx.x & 63;
    const int ll = lane & (SUBW - 1);
    const int dpb = 256 / SUBW;
    const int dst = blockIdx.x * dpb + threadIdx.x / SUBW;
    if (dst >= nnodes) return;
    const int base = lane & ~(SUBW - 1);
    const int beg = offsets[dst], end = offsets[dst + 1];
    float ax = 0.f, ay = 0.f;

    auto rowp = [&](unsigned key) {
        return (const unsigned*)(T + ((size_t)(key & 15) * nnodes + (key >> 4)) * NOUT);
    };

    for (int i = beg; i < end; i += SUBW) {
        int cnt = min(SUBW, end - i);
        uint2 pl = make_uint2(0u, 0u);
        if (ll < cnt) pl = payload[i + ll];
        int j = 0;
        for (; j + 4 <= cnt; j += 4) {
            unsigned k0 = (unsigned)__shfl((int)pl.x, base + j);
            unsigned k1 = (unsigned)__shfl((int)pl.x, base + j + 1);
            unsigned k2 = (unsigned)__shfl((int)pl.x, base + j + 2);
            unsigned k3 = (unsigned)__shfl((int)pl.x, base + j + 3);
            float n0 = __builtin_bit_cast(float, (unsigned)__shfl((int)pl.y, base + j));
            float n1 = __builtin_bit_cast(float, (unsigned)__shfl((int)pl.y, base + j + 1));
            float n2 = __builtin_bit_cast(float, (unsigned)__shfl((int)pl.y, base + j + 2));
            float n3 = __builtin_bit_cast(float, (unsigned)__shfl((int)pl.y, base + j + 3));
            unsigned v0 = rowp(k0)[ll];
            unsigned v1 = rowp(k1)[ll];
            unsigned v2 = rowp(k2)[ll];
            unsigned v3 = rowp(k3)[ll];
            ax = fmaf(lo16(v0), n0, ax); ay = fmaf(hi16(v0), n0, ay);
            ax = fmaf(lo16(v1), n1, ax); ay = fmaf(hi16(v1), n1, ay);
            ax = fmaf(lo16(v2), n2, ax); ay = fmaf(hi16(v2), n2, ay);
            ax = fmaf(lo16(v3), n3, ax); ay = fmaf(hi16(v3), n3, ay);
        }
        for (; j < cnt; j++) {
            unsigned k = (unsigned)__shfl((int)pl.x, base + j);
            float nm = __builtin_bit_cast(float, (unsigned)__shfl((int)pl.y, base + j));
            unsigned v = rowp(k)[ll];
            ax = fmaf(lo16(v), nm, ax);
            ay = fmaf(hi16(v), nm, ay);
        }
    }
    if (OUTMODE == 0) {
        ((unsigned*)out)[(size_t)dst * SUBW + ll] = pack2(fmaxf(ax, 0.f), fmaxf(ay, 0.f));
    } else {
        if (*flagp) {
            ((unsigned*)out)[(size_t)dst * SUBW + ll] = pack2(ax, ay);
        } else {
            float2 v;
            v.x = ax; v.y = ay;
            ((float2*)out)[(size_t)dst * SUBW + ll] = v;
        }
    }
}

// ---------------- fallback path (chunked + atomics, node-major t) ----------------
template <int NOUT, int AMODE>
__global__ __launch_bounds__(256) void gemm_rel(const void* __restrict__ Asrc,
                                                const unsigned short* __restrict__ Wt,
                                                unsigned short* __restrict__ T, int nnodes,
                                                int rbase, const int* __restrict__ flagp) {
    constexpr int LDA = 136;
    __shared__ unsigned short lA[64 * LDA];
    __shared__ unsigned short lB[NOUT * LDA];
    const int tid = threadIdx.x;
    const int node0 = blockIdx.x * 64;
    const int rel = rbase + blockIdx.y;
    const int Gr = gridDim.y;
    const int flag = (AMODE == 0) ? *flagp : 1;

    for (int i = tid; i < 64 * 16; i += 256) {
        int row = i >> 4, seg = i & 15;
        int node = node0 + row;
        uint4 v = make_uint4(0u, 0u, 0u, 0u);
        if (node < nnodes) {
            if (AMODE == 1) {
                const float* p = (const float*)Asrc + (size_t)node * 128 + seg * 8;
                float4 f0 = ((const float4*)p)[0];
                float4 f1 = ((const float4*)p)[1];
                v.x = pack2(fmaxf(f0.x, 0.f), fmaxf(f0.y, 0.f));
                v.y = pack2(fmaxf(f0.z, 0.f), fmaxf(f0.w, 0.f));
                v.z = pack2(fmaxf(f1.x, 0.f), fmaxf(f1.y, 0.f));
                v.w = pack2(fmaxf(f1.z, 0.f), fmaxf(f1.w, 0.f));
            } else if (flag) {
                v = *(const uint4*)((const unsigned short*)Asrc + (size_t)node * 128 + seg * 8);
            } else {
                const float* p = (const float*)Asrc + (size_t)node * 128 + seg * 8;
                float4 f0 = ((const float4*)p)[0];
                float4 f1 = ((const float4*)p)[1];
                v.x = pack2(f0.x, f0.y);
                v.y = pack2(f0.z, f0.w);
                v.z = pack2(f1.x, f1.y);
                v.w = pack2(f1.z, f1.w);
            }
        }
        *(uint4*)(lA + row * LDA + seg * 8) = v;
    }
    for (int i = tid; i < NOUT * 16; i += 256) {
        int o = i >> 4, seg = i & 15;
        *(uint4*)(lB + o * LDA + seg * 8) =
            *(const uint4*)(Wt + ((size_t)rel * NOUT + o) * 128 + seg * 8);
    }
    __syncthreads();

    const int w = tid >> 6, lane = tid & 63;
    const int quad = lane >> 4, mr = lane & 15;
    constexpr int NT = NOUT / 16;
    f32x4 acc[NT];
#pragma unroll
    for (int t = 0; t < NT; t++) acc[t] = 0.f;
    const unsigned short* pa = lA + (w * 16 + mr) * LDA + quad * 8;
    const unsigned short* pb = lB + mr * LDA + quad * 8;
#pragma unroll
    for (int kk = 0; kk < 4; kk++) {
        bf16x8 a = *(const bf16x8*)(pa + kk * 32);
#pragma unroll
        for (int nt = 0; nt < NT; nt++) {
            bf16x8 b = *(const bf16x8*)(pb + nt * 16 * LDA + kk * 32);
            acc[nt] = __builtin_amdgcn_mfma_f32_16x16x32_bf16(a, b, acc[nt], 0, 0, 0);
        }
    }
#pragma unroll
    for (int nt = 0; nt < NT; nt++)
#pragma unroll
        for (int reg = 0; reg < 4; reg++) {
            int node = node0 + w * 16 + quad * 4 + reg;
            if (node < nnodes)
                T[((size_t)node * Gr + blockIdx.y) * NOUT + nt * 16 + mr] = f2bf(acc[nt][reg]);
        }
}

template <int NOUT>
__global__ void scatter_k(const unsigned short* __restrict__ T, int Gr, int rbase,
                          const void* __restrict__ nrm, const int* __restrict__ flagp,
                          const int* __restrict__ src, const int* __restrict__ dst,
                          const int* __restrict__ et, float* __restrict__ accum, int nedges) {
    constexpr int LPE = NOUT / 2;
    const int flag = *flagp;
    const int epb = 256 / LPE;
    const int sub = threadIdx.x % LPE;
    const int slot = threadIdx.x / LPE;
    for (int e = blockIdx.x * epb + slot; e < nedges; e += gridDim.x * epb) {
        int g = et[e] - rbase;
        if (g < 0 || g >= Gr) continue;
        int s = src[e], d = dst[e];
        float nm = flag ? bf2f(((const unsigned short*)nrm)[e]) : ((const float*)nrm)[e];
        unsigned pv = ((const unsigned*)(T + ((size_t)s * Gr + g) * NOUT))[sub];
        float* p = accum + (size_t)d * NOUT + sub * 2;
        unsafeAtomicAdd(p, lo16(pv) * nm);
        unsafeAtomicAdd(p + 1, hi16(pv) * nm);
    }
}

__global__ void write_out(const float* __restrict__ acc, void* __restrict__ dout, int n,
                          const int* __restrict__ flagp) {
    int flag = *flagp;
    int i = blockIdx.x * 256 + threadIdx.x;
    if (i >= n) return;
    float v = acc[i];
    if (flag) ((unsigned short*)dout)[i] = f2bf(v);
    else      ((float*)dout)[i] = v;
}

extern "C" void kernel_launch(void* const* d_in, const int* in_sizes, int n_in,
                              void* d_out, int out_size, void* d_ws, size_t ws_size,
                              hipStream_t stream) {
    const void* feat = d_in[0];
    const void* norm = d_in[1];
    const void* W1 = d_in[2];
    const void* W2 = d_in[3];
    const int* src = (const int*)d_in[4];
    const int* dst = (const int*)d_in[5];
    const int* et  = (const int*)d_in[6];

    const int nnodes = in_sizes[0] / 128;
    const int nedges = in_sizes[1];

    char* ws = (char*)d_ws;
    size_t off = 0;
    auto alloc = [&](size_t bytes) { size_t o = off; off += (bytes + 255) & ~255ULL; return o; };
    size_t off_flag = alloc(4);
    size_t off_w1t  = alloc((size_t)R_NUM * 128 * 128 * 2);
    size_t off_w2t  = alloc((size_t)R_NUM * 64 * 128 * 2);

    int* flagp = (int*)(ws + off_flag);
    unsigned short* w1t = (unsigned short*)(ws + off_w1t);
    unsigned short* w2t = (unsigned short*)(ws + off_w2t);

    // fast-path layout
    size_t f_off = off;
    auto falloc = [&](size_t bytes) { size_t o = f_off; f_off += (bytes + 255) & ~255ULL; return o; };
    size_t off_offs = falloc((size_t)(nnodes + 1) * 4);
    size_t off_curs = falloc((size_t)nnodes * 4);
    size_t off_cnt  = falloc((size_t)nnodes * 4);
    size_t off_bsum = falloc(1024 * 4);
    size_t off_boff = falloc(1024 * 4);
    size_t off_pay  = falloc((size_t)nedges * 8);
    size_t off_hbf  = falloc((size_t)nnodes * 128 * 2);
    size_t off_t    = falloc((size_t)nnodes * R_NUM * 128 * 2);
    const int nb = (nnodes + 1023) / 1024;
    bool fast = (f_off <= ws_size) && (nb <= 1024);

    const int gx = (nnodes + 63) / 64;
    const int ntr = R_NUM * 128 * 128 + R_NUM * 128 * 64;

    detect_dtype<<<1, 256, 0, stream>>>((const unsigned short*)feat, flagp);
    transpose_both<<<(ntr + 255) / 256, 256, 0, stream>>>(W1, W2, w1t, w2t, flagp);

    if (fast) {
        int* offs = (int*)(ws + off_offs);
        int* curs = (int*)(ws + off_curs);
        int* cnt  = (int*)(ws + off_cnt);
        int* bsum = (int*)(ws + off_bsum);
        int* boff = (int*)(ws + off_boff);
        uint2* pay = (uint2*)(ws + off_pay);
        unsigned short* hbf = (unsigned short*)(ws + off_hbf);
        unsigned short* t = (unsigned short*)(ws + off_t);

        hipMemsetAsync(cnt, 0, (size_t)nnodes * 4, stream);
        hist_dst<<<(nedges + 255) / 256, 256, 0, stream>>>(dst, cnt, nedges);
        scan_phase1<<<nb, 256, 0, stream>>>(cnt, bsum, nnodes);
        scan_phase2<<<1, 1024, 0, stream>>>(bsum, boff, nb);
        scan_phase3<<<nb, 256, 0, stream>>>(cnt, boff, offs, curs, nnodes);
        fill_payload<<<(nedges + 255) / 256, 256, 0, stream>>>(src, dst, et, norm, flagp,
                                                               curs, pay, nedges);

        gemm_nb<128, 0><<<gx, 256, 0, stream>>>(feat, w1t, t, nnodes, flagp);
        gather_seg<128, 0><<<(nnodes + 3) / 4, 256, 0, stream>>>(t, offs, pay, hbf, nnodes, flagp);
        gemm_nb<64, 2><<<gx, 256, 0, stream>>>(hbf, w2t, t, nnodes, flagp);
        gather_seg<64, 1><<<(nnodes + 7) / 8, 256, 0, stream>>>(t, offs, pay, d_out, nnodes, flagp);
        return;
    }

    // fallback: chunked atomic path
    size_t off_hpre = alloc((size_t)nnodes * 128 * 4);
    size_t off_oacc = alloc((size_t)nnodes * 64 * 4);
    size_t t_cap = (ws_size > off) ? (ws_size - off) : 0;
    auto pick_gr = [&](int ncol) {
        int gr = 0;
        for (int g = 16; g >= 1; g >>= 1)
            if ((size_t)nnodes * g * ncol * 2 <= t_cap) { gr = g; break; }
        return gr;
    };
    int Gr1 = pick_gr(128);
    int Gr2 = pick_gr(64);
    if (Gr1 < 1 || Gr2 < 1) {
        hipMemsetAsync(d_out, 0x42, (size_t)out_size * 2, stream);
        return;
    }
    float* hpre = (float*)(ws + off_hpre);
    float* oacc = (float*)(ws + off_oacc);
    unsigned short* t = (unsigned short*)(ws + off);

    hipMemsetAsync(hpre, 0, (size_t)nnodes * 128 * 4, stream);
    hipMemsetAsync(oacc, 0, (size_t)nnodes * 64 * 4, stream);
    for (int rb = 0; rb < R_NUM; rb += Gr1) {
        gemm_rel<128, 0><<<dim3(gx, Gr1), 256, 0, stream>>>(feat, w1t, t, nnodes, rb, flagp);
        scatter_k<128><<<4096, 256, 0, stream>>>(t, Gr1, rb, norm, flagp, src, dst, et, hpre, nedges);
    }
    for (int rb = 0; rb < R_NUM; rb += Gr2) {
        gemm_rel<64, 1><<<dim3(gx, Gr2), 256, 0, stream>>>(hpre, w2t, t, nnodes, rb, flagp);
        scatter_k<64><<<4096, 256, 0, stream>>>(t, Gr2, rb, norm, flagp, src, dst, et, oacc, nedges);
    }
    int nout = nnodes * 64;
    write_out<<<(nout + 255) / 256, 256, 0, stream>>>(oacc, d_out, nout, flagp);
}